// Round 1
// baseline (50436.057 us; speedup 1.0000x reference)
//
#include <hip/hip_runtime.h>
#include <cstdint>
#include <cstddef>

#define T_STEPS 2048
#define BATCH   16
#define NIN_D   1024
#define NH_D    1024
#define G_D     4096
#define MROWS   32768   // T*B
#define NBLK    256     // scan workgroups

typedef short short8 __attribute__((ext_vector_type(8)));
typedef float f32x4  __attribute__((ext_vector_type(4)));

__device__ __forceinline__ unsigned short f2bf(float f) {
  unsigned u = __builtin_bit_cast(unsigned, f);
  u += 0x7FFFu + ((u >> 16) & 1u);          // RNE
  return (unsigned short)(u >> 16);
}
__device__ __forceinline__ float bf2f(unsigned short h) {
  unsigned u = ((unsigned)h) << 16;
  return __builtin_bit_cast(float, u);
}
__device__ __forceinline__ float sigmoidf_(float x) { return 1.0f / (1.0f + __expf(-x)); }
__device__ __forceinline__ float tanhf_(float x)    { return 2.0f / (1.0f + __expf(-2.0f * x)) - 1.0f; }

// ---------------- cast X: f32 -> bf16, vectorized ----------------
__global__ void cast_f32_bf16(const float* __restrict__ in, unsigned short* __restrict__ out, int n4) {
  int idx = blockIdx.x * blockDim.x + threadIdx.x;
  if (idx < n4) {
    float4 v = ((const float4*)in)[idx];
    ushort4 o;
    o.x = f2bf(v.x); o.y = f2bf(v.y); o.z = f2bf(v.z); o.w = f2bf(v.w);
    ((ushort4*)out)[idx] = o;
  }
}

// ---------------- transpose+cast W [1024][4096] f32 -> WT [4096][1024] bf16 ----------------
__global__ void transpose_cast(const float* __restrict__ in, unsigned short* __restrict__ out) {
  __shared__ float tile[32][33];
  const int gx = blockIdx.x * 32;   // col base in `in` (g)
  const int gy = blockIdx.y * 32;   // row base in `in` (k)
  const int tx = threadIdx.x, ty = threadIdx.y;   // (32,8)
  #pragma unroll
  for (int p = 0; p < 4; ++p)
    tile[ty + p * 8][tx] = in[(size_t)(gy + ty + p * 8) * G_D + gx + tx];
  __syncthreads();
  #pragma unroll
  for (int p = 0; p < 4; ++p)
    out[(size_t)(gx + ty + p * 8) * NIN_D + gy + tx] = f2bf(tile[tx][ty + p * 8]);
}

// ---------------- init: zero barrier counter, hbuf[0] = bf16(h0) ----------------
__global__ void init_state(const float* __restrict__ h0, unsigned short* __restrict__ hbuf,
                           unsigned* __restrict__ cnt) {
  int idx = blockIdx.x * blockDim.x + threadIdx.x;
  if (idx == 0) *cnt = 0u;
  if (idx < BATCH * NH_D) hbuf[idx] = f2bf(h0[idx]);
}

// ---------------- intern GEMM: C[m][g] = A[m][:] . BT[g][:] + bias[g] (bf16 out) ----------------
// A = Xbf [32768][1024], Bt = WinT [4096][1024], both row-major k-contiguous.
__global__ __launch_bounds__(256) void gemm_intern(
    const unsigned short* __restrict__ A,
    const unsigned short* __restrict__ Bt,
    const float* __restrict__ bias,
    unsigned short* __restrict__ Out) {
  __shared__ unsigned short As[128 * 72];   // 64 data + 8 pad bf16 per row (144B, 16B-aligned)
  __shared__ unsigned short Bs[128 * 72];
  const int tid  = threadIdx.x;
  const int lane = tid & 63;
  const int w    = tid >> 6;
  const int r16  = lane & 15;
  const int kgrp = lane >> 4;
  const int wrow = (w >> 1) * 64;
  const int wcol = (w & 1) * 64;
  const int bx = blockIdx.x;   // N tile (0..31)
  const int by = blockIdx.y;   // M tile (0..255)

  const unsigned short* Ag = A  + (size_t)by * 128 * NIN_D;
  const unsigned short* Bg = Bt + (size_t)bx * 128 * NIN_D;
  const int trow = tid >> 3;          // 0..31
  const int tcol = (tid & 7) * 8;     // 0..56

  f32x4 acc[4][4];
  #pragma unroll
  for (int m = 0; m < 4; ++m)
    #pragma unroll
    for (int n = 0; n < 4; ++n)
      acc[m][n] = (f32x4){0.f, 0.f, 0.f, 0.f};

  for (int kt = 0; kt < 16; ++kt) {
    const int kb = kt * 64;
    __syncthreads();
    #pragma unroll
    for (int p = 0; p < 4; ++p) {
      const int r = trow + p * 32;
      *(uint4*)(&As[r * 72 + tcol]) = *(const uint4*)(Ag + (size_t)r * NIN_D + kb + tcol);
      *(uint4*)(&Bs[r * 72 + tcol]) = *(const uint4*)(Bg + (size_t)r * NIN_D + kb + tcol);
    }
    __syncthreads();
    #pragma unroll
    for (int kk = 0; kk < 2; ++kk) {
      const int ko = kk * 32 + kgrp * 8;
      short8 af[4], bq[4];
      #pragma unroll
      for (int m = 0; m < 4; ++m)
        af[m] = *(const short8*)(&As[(wrow + m * 16 + r16) * 72 + ko]);
      #pragma unroll
      for (int n = 0; n < 4; ++n)
        bq[n] = *(const short8*)(&Bs[(wcol + n * 16 + r16) * 72 + ko]);
      #pragma unroll
      for (int m = 0; m < 4; ++m)
        #pragma unroll
        for (int n = 0; n < 4; ++n)
          acc[m][n] = __builtin_amdgcn_mfma_f32_16x16x32_bf16(af[m], bq[n], acc[m][n], 0, 0, 0);
    }
  }
  // epilogue: C/D layout col=lane&15, row=(lane>>4)*4+i
  #pragma unroll
  for (int n = 0; n < 4; ++n) {
    const int col = bx * 128 + wcol + n * 16 + r16;
    const float bv = bias[col];
    #pragma unroll
    for (int m = 0; m < 4; ++m) {
      const int row0 = by * 128 + wrow + m * 16 + kgrp * 4;
      #pragma unroll
      for (int i = 0; i < 4; ++i)
        Out[(size_t)(row0 + i) * G_D + col] = f2bf(acc[m][n][i] + bv);
    }
  }
}

// ---------------- persistent LSTM scan ----------------
// 256 wgs x 64 threads. wg owns hidden units j0..j0+3 (16 gate cols).
// W_re^T slice resident in LDS; h double-buffered bf16 in global; c in registers.
__global__ __launch_bounds__(64) void lstm_scan(
    const unsigned short* __restrict__ intern, // [32768][4096] bf16
    const unsigned short* __restrict__ WreT,   // [4096][1024] bf16
    const float* __restrict__ msk,             // [2048][16]
    const float* __restrict__ c0,              // [16][1024]
    unsigned short* __restrict__ hbuf,         // [2][16][1024] bf16
    unsigned* __restrict__ cnt,
    float* __restrict__ Y, float* __restrict__ C, float* __restrict__ D) {
  const int wg = blockIdx.x;
  const int lane = threadIdx.x;
  const int j0 = wg * 4;
  __shared__ unsigned short w_s[16][1032];  // row stride 2064B: 16B-aligned, 2-way banks (free)
  __shared__ float z_s[16][20];

  const int r16 = lane & 15, kgrp = lane >> 4;
  // load W slice: local col c -> gate q=c>>2, hidden jj=c&3, g = q*1024 + j0 + jj
  #pragma unroll
  for (int c = 0; c < 16; ++c) {
    const int g = (c >> 2) * NH_D + j0 + (c & 3);
    const unsigned short* src = WreT + (size_t)g * NH_D;
    *(uint4*)(&w_s[c][lane * 8])       = *(const uint4*)(src + lane * 8);
    *(uint4*)(&w_s[c][512 + lane * 8]) = *(const uint4*)(src + 512 + lane * 8);
  }
  const int gb = lane >> 2, gj = lane & 3;   // gate-stage mapping: (batch, hidden-offset)
  float creg = c0[gb * NH_D + j0 + gj];
  __syncthreads();

  for (int t = 0; t < T_STEPS; ++t) {
    const unsigned short* hp = hbuf + (size_t)(t & 1) * (BATCH * NH_D);
    f32x4 acc = (f32x4){0.f, 0.f, 0.f, 0.f};
    #pragma unroll 8
    for (int kc = 0; kc < 32; ++kc) {
      const int k0 = kc * 32 + kgrp * 8;
      short8 a = *(const short8*)(hp + r16 * NH_D + k0);        // A: h[b=r16][k]
      short8 b = *(const short8*)(&w_s[r16][k0]);               // B: W[k][col=r16]
      acc = __builtin_amdgcn_mfma_f32_16x16x32_bf16(a, b, acc, 0, 0, 0);
    }
    // z = acc + intern, staged to LDS in C-frag layout (row b = kgrp*4+i, col = r16)
    const unsigned short* ip = intern + (size_t)t * BATCH * G_D;
    const int gcol = (r16 >> 2) * NH_D + j0 + (r16 & 3);
    #pragma unroll
    for (int i = 0; i < 4; ++i) {
      const int bb = kgrp * 4 + i;
      z_s[bb][r16] = acc[i] + bf2f(ip[(size_t)bb * G_D + gcol]);
    }
    __syncthreads();
    // gates: lane = (b=gb, jj=gj); cols: q*4+jj
    const float zc = z_s[gb][gj];
    const float zi = z_s[gb][4 + gj];
    const float zf = z_s[gb][8 + gj];
    const float zo = z_s[gb][12 + gj];
    const float mval = msk[t * BATCH + gb];
    const float cell = tanhf_(zc);
    const float ig = sigmoidf_(zi);
    const float fg = sigmoidf_(zf);
    const float og = sigmoidf_(zo);
    const float cn = fg * creg + ig * cell;
    const float yn = og * tanhf_(cn);
    const float cnew = mval * cn + (1.0f - mval) * creg;
    const float ynew = mval * yn;
    creg = cnew;
    const size_t ob = ((size_t)t * BATCH + gb) * NH_D + j0 + gj;
    Y[ob] = ynew;
    C[ob] = cnew;
    hbuf[(size_t)((t + 1) & 1) * (BATCH * NH_D) + gb * NH_D + j0 + gj] = f2bf(ynew);
    __syncthreads();
    if (t < T_STEPS - 1) {
      __threadfence();  // release: flush our h writes toward coherence point
      if (lane == 0)
        __hip_atomic_fetch_add(cnt, 1u, __ATOMIC_RELEASE, __HIP_MEMORY_SCOPE_AGENT);
      const unsigned target = (unsigned)(t + 1) * (unsigned)NBLK;
      while (__hip_atomic_load(cnt, __ATOMIC_RELAXED, __HIP_MEMORY_SCOPE_AGENT) < target)
        __builtin_amdgcn_s_sleep(2);
      __threadfence();  // acquire: invalidate stale cached h
    }
  }
  D[gb * NH_D + j0 + gj] = creg;
}

extern "C" void kernel_launch(void* const* d_in, const int* in_sizes, int n_in,
                              void* d_out, int out_size, void* d_ws, size_t ws_size,
                              hipStream_t stream) {
  const float* X     = (const float*)d_in[0];
  const float* imask = (const float*)d_in[1];
  const float* h0    = (const float*)d_in[2];
  const float* c0    = (const float*)d_in[3];
  const float* Win   = (const float*)d_in[4];
  const float* Wre   = (const float*)d_in[5];
  const float* bias  = (const float*)d_in[6];
  float* out = (float*)d_out;

  char* ws = (char*)d_ws;
  // ws layout (all 16B-aligned offsets)
  unsigned short* Xbf    = (unsigned short*)(ws);                         // 64 MB
  unsigned short* WinT   = (unsigned short*)(ws + 67108864);              // 8 MB
  unsigned short* WreT   = (unsigned short*)(ws + 75497472);              // 8 MB
  unsigned short* intern = (unsigned short*)(ws + 83886080);              // 256 MB
  unsigned short* hbuf   = (unsigned short*)(ws + 352321536);             // 64 KB
  unsigned*       cnt    = (unsigned*)(ws + 352387072);

  float* Y = out;
  float* C = out + (size_t)T_STEPS * BATCH * NH_D;
  float* D = out + (size_t)2 * T_STEPS * BATCH * NH_D;

  // 1) casts / transposes
  {
    int n4 = (MROWS * NIN_D) / 4;
    cast_f32_bf16<<<dim3((n4 + 255) / 256), dim3(256), 0, stream>>>(X, Xbf, n4);
  }
  transpose_cast<<<dim3(G_D / 32, NIN_D / 32), dim3(32, 8), 0, stream>>>(Win, WinT);
  transpose_cast<<<dim3(G_D / 32, NH_D / 32),  dim3(32, 8), 0, stream>>>(Wre, WreT);
  init_state<<<dim3((BATCH * NH_D + 255) / 256), dim3(256), 0, stream>>>(h0, hbuf, cnt);

  // 2) intern = X @ W_in + b
  gemm_intern<<<dim3(G_D / 128, MROWS / 128), dim3(256), 0, stream>>>(Xbf, WinT, bias, intern);

  // 3) sequential scan (persistent, one wave per CU)
  lstm_scan<<<dim3(NBLK), dim3(64), 0, stream>>>(intern, WreT, imask, c0, hbuf, cnt, Y, C, D);
}

// Round 2
// 24337.843 us; speedup vs baseline: 2.0723x; 2.0723x over previous
//
#include <hip/hip_runtime.h>
#include <cstdint>
#include <cstddef>

#define T_STEPS 2048
#define BATCH   16
#define NIN_D   1024
#define NH_D    1024
#define G_D     4096
#define MROWS   32768   // T*B
#define NBLK    256     // scan workgroups
#define FLAG_STRIDE 16  // dwords -> 64B padding per flag

typedef short short8 __attribute__((ext_vector_type(8)));
typedef float f32x4  __attribute__((ext_vector_type(4)));

__device__ __forceinline__ unsigned short f2bf(float f) {
  unsigned u = __builtin_bit_cast(unsigned, f);
  u += 0x7FFFu + ((u >> 16) & 1u);          // RNE
  return (unsigned short)(u >> 16);
}
__device__ __forceinline__ float bf2f(unsigned short h) {
  unsigned u = ((unsigned)h) << 16;
  return __builtin_bit_cast(float, u);
}
__device__ __forceinline__ float sigmoidf_(float x) { return 1.0f / (1.0f + __expf(-x)); }
__device__ __forceinline__ float tanhf_(float x)    { return 2.0f / (1.0f + __expf(-2.0f * x)) - 1.0f; }

// ---------------- cast X: f32 -> bf16, vectorized ----------------
__global__ void cast_f32_bf16(const float* __restrict__ in, unsigned short* __restrict__ out, int n4) {
  int idx = blockIdx.x * blockDim.x + threadIdx.x;
  if (idx < n4) {
    float4 v = ((const float4*)in)[idx];
    ushort4 o;
    o.x = f2bf(v.x); o.y = f2bf(v.y); o.z = f2bf(v.z); o.w = f2bf(v.w);
    ((ushort4*)out)[idx] = o;
  }
}

// ---------------- transpose+cast W [1024][4096] f32 -> WT [4096][1024] bf16 ----------------
__global__ void transpose_cast(const float* __restrict__ in, unsigned short* __restrict__ out) {
  __shared__ float tile[32][33];
  const int gx = blockIdx.x * 32;   // col base in `in` (g)
  const int gy = blockIdx.y * 32;   // row base in `in` (k)
  const int tx = threadIdx.x, ty = threadIdx.y;   // (32,8)
  #pragma unroll
  for (int p = 0; p < 4; ++p)
    tile[ty + p * 8][tx] = in[(size_t)(gy + ty + p * 8) * G_D + gx + tx];
  __syncthreads();
  #pragma unroll
  for (int p = 0; p < 4; ++p)
    out[(size_t)(gx + ty + p * 8) * NIN_D + gy + tx] = f2bf(tile[tx][ty + p * 8]);
}

// ---------------- init: zero flags, hbuf[0] = bf16(h0) ----------------
__global__ void init_state(const float* __restrict__ h0, unsigned short* __restrict__ hbuf,
                           unsigned* __restrict__ flags) {
  int idx = blockIdx.x * blockDim.x + threadIdx.x;
  if (idx < NBLK * FLAG_STRIDE) flags[idx] = 0u;
  if (idx < BATCH * NH_D) hbuf[idx] = f2bf(h0[idx]);
}

// ---------------- intern GEMM: C[m][g] = A[m][:] . BT[g][:] + bias[g] (bf16 out) ----------------
__global__ __launch_bounds__(256) void gemm_intern(
    const unsigned short* __restrict__ A,
    const unsigned short* __restrict__ Bt,
    const float* __restrict__ bias,
    unsigned short* __restrict__ Out) {
  __shared__ unsigned short As[128 * 72];
  __shared__ unsigned short Bs[128 * 72];
  const int tid  = threadIdx.x;
  const int lane = tid & 63;
  const int w    = tid >> 6;
  const int r16  = lane & 15;
  const int kgrp = lane >> 4;
  const int wrow = (w >> 1) * 64;
  const int wcol = (w & 1) * 64;
  const int bx = blockIdx.x;
  const int by = blockIdx.y;

  const unsigned short* Ag = A  + (size_t)by * 128 * NIN_D;
  const unsigned short* Bg = Bt + (size_t)bx * 128 * NIN_D;
  const int trow = tid >> 3;
  const int tcol = (tid & 7) * 8;

  f32x4 acc[4][4];
  #pragma unroll
  for (int m = 0; m < 4; ++m)
    #pragma unroll
    for (int n = 0; n < 4; ++n)
      acc[m][n] = (f32x4){0.f, 0.f, 0.f, 0.f};

  for (int kt = 0; kt < 16; ++kt) {
    const int kb = kt * 64;
    __syncthreads();
    #pragma unroll
    for (int p = 0; p < 4; ++p) {
      const int r = trow + p * 32;
      *(uint4*)(&As[r * 72 + tcol]) = *(const uint4*)(Ag + (size_t)r * NIN_D + kb + tcol);
      *(uint4*)(&Bs[r * 72 + tcol]) = *(const uint4*)(Bg + (size_t)r * NIN_D + kb + tcol);
    }
    __syncthreads();
    #pragma unroll
    for (int kk = 0; kk < 2; ++kk) {
      const int ko = kk * 32 + kgrp * 8;
      short8 af[4], bq[4];
      #pragma unroll
      for (int m = 0; m < 4; ++m)
        af[m] = *(const short8*)(&As[(wrow + m * 16 + r16) * 72 + ko]);
      #pragma unroll
      for (int n = 0; n < 4; ++n)
        bq[n] = *(const short8*)(&Bs[(wcol + n * 16 + r16) * 72 + ko]);
      #pragma unroll
      for (int m = 0; m < 4; ++m)
        #pragma unroll
        for (int n = 0; n < 4; ++n)
          acc[m][n] = __builtin_amdgcn_mfma_f32_16x16x32_bf16(af[m], bq[n], acc[m][n], 0, 0, 0);
    }
  }
  #pragma unroll
  for (int n = 0; n < 4; ++n) {
    const int col = bx * 128 + wcol + n * 16 + r16;
    const float bv = bias[col];
    #pragma unroll
    for (int m = 0; m < 4; ++m) {
      const int row0 = by * 128 + wrow + m * 16 + kgrp * 4;
      #pragma unroll
      for (int i = 0; i < 4; ++i)
        Out[(size_t)(row0 + i) * G_D + col] = f2bf(acc[m][n][i] + bv);
    }
  }
}

// ---------------- persistent LSTM scan ----------------
// 256 wgs x 64 threads (1 wave). wg owns hidden units j0..j0+3 (16 gate cols).
// Sync: per-wg flag (own cacheline) release-stored with step number; every wg
// polls all 256 flags (reads only, no RMW contention). Directional fences.
__global__ __launch_bounds__(64) void lstm_scan(
    const unsigned short* __restrict__ intern, // [32768][4096] bf16
    const unsigned short* __restrict__ WreT,   // [4096][1024] bf16
    const float* __restrict__ msk,             // [2048][16]
    const float* __restrict__ c0,              // [16][1024]
    unsigned short* __restrict__ hbuf,         // [2][16][1024] bf16
    unsigned* __restrict__ flags,              // [256*FLAG_STRIDE]
    float* __restrict__ Y, float* __restrict__ C, float* __restrict__ D) {
  const int wg = blockIdx.x;
  const int lane = threadIdx.x;
  const int j0 = wg * 4;
  __shared__ unsigned short w_s[16][1032];
  __shared__ float z_s[16][20];

  const int r16 = lane & 15, kgrp = lane >> 4;
  #pragma unroll
  for (int c = 0; c < 16; ++c) {
    const int g = (c >> 2) * NH_D + j0 + (c & 3);
    const unsigned short* src = WreT + (size_t)g * NH_D;
    *(uint4*)(&w_s[c][lane * 8])       = *(const uint4*)(src + lane * 8);
    *(uint4*)(&w_s[c][512 + lane * 8]) = *(const uint4*)(src + 512 + lane * 8);
  }
  const int gb = lane >> 2, gj = lane & 3;
  float creg = c0[gb * NH_D + j0 + gj];
  const int gcol = (r16 >> 2) * NH_D + j0 + (r16 & 3);

  // prefetch intern[0] + mask[0] into registers
  unsigned short ipr[4];
  #pragma unroll
  for (int i = 0; i < 4; ++i)
    ipr[i] = intern[(size_t)(kgrp * 4 + i) * G_D + gcol];
  float mreg = msk[gb];
  __syncthreads();

  for (int t = 0; t < T_STEPS; ++t) {
    const unsigned short* hp = hbuf + (size_t)(t & 1) * (BATCH * NH_D);
    f32x4 acc4[4];
    #pragma unroll
    for (int q = 0; q < 4; ++q) acc4[q] = (f32x4){0.f, 0.f, 0.f, 0.f};
    #pragma unroll 8
    for (int kc = 0; kc < 32; ++kc) {
      const int k0 = kc * 32 + kgrp * 8;
      short8 a = *(const short8*)(hp + r16 * NH_D + k0);        // A: h[b=r16][k]
      short8 b = *(const short8*)(&w_s[r16][k0]);               // B: W[k][col=r16]
      acc4[kc & 3] = __builtin_amdgcn_mfma_f32_16x16x32_bf16(a, b, acc4[kc & 3], 0, 0, 0);
    }
    f32x4 acc = (acc4[0] + acc4[1]) + (acc4[2] + acc4[3]);

    // z = acc + intern, staged to LDS in C-frag layout (row b = kgrp*4+i, col = r16)
    #pragma unroll
    for (int i = 0; i < 4; ++i)
      z_s[kgrp * 4 + i][r16] = acc[i] + bf2f(ipr[i]);
    __syncthreads();
    const float zc = z_s[gb][gj];
    const float zi = z_s[gb][4 + gj];
    const float zf = z_s[gb][8 + gj];
    const float zo = z_s[gb][12 + gj];
    __syncthreads();

    const float cell = tanhf_(zc);
    const float ig = sigmoidf_(zi);
    const float fg = sigmoidf_(zf);
    const float og = sigmoidf_(zo);
    const float cn = fg * creg + ig * cell;
    const float yn = og * tanhf_(cn);
    const float cnew = mreg * cn + (1.0f - mreg) * creg;
    const float ynew = mreg * yn;
    creg = cnew;

    // critical path: h store -> release fence -> flag store
    hbuf[(size_t)((t + 1) & 1) * (BATCH * NH_D) + gb * NH_D + j0 + gj] = f2bf(ynew);
    __builtin_amdgcn_fence(__ATOMIC_RELEASE, "agent");
    if (lane == 0)
      __hip_atomic_store(&flags[wg * FLAG_STRIDE], (unsigned)(t + 1),
                         __ATOMIC_RELAXED, __HIP_MEMORY_SCOPE_AGENT);

    // off-critical-path: outputs (nontemporal, read by nobody on-device)
    const size_t ob = ((size_t)t * BATCH + gb) * NH_D + j0 + gj;
    __builtin_nontemporal_store(ynew, &Y[ob]);
    __builtin_nontemporal_store(cnew, &C[ob]);

    if (t < T_STEPS - 1) {
      // prefetch next intern + mask into registers (overlaps with poll)
      const unsigned short* ipn = intern + (size_t)(t + 1) * BATCH * G_D;
      #pragma unroll
      for (int i = 0; i < 4; ++i)
        ipr[i] = ipn[(size_t)(kgrp * 4 + i) * G_D + gcol];
      mreg = msk[(t + 1) * BATCH + gb];

      // poll all 256 flags: lane l watches 4 flags, no RMW anywhere
      const unsigned tgt = (unsigned)(t + 1);
      for (;;) {
        unsigned a0 = __hip_atomic_load(&flags[(lane      ) * FLAG_STRIDE], __ATOMIC_RELAXED, __HIP_MEMORY_SCOPE_AGENT);
        unsigned a1 = __hip_atomic_load(&flags[(lane +  64) * FLAG_STRIDE], __ATOMIC_RELAXED, __HIP_MEMORY_SCOPE_AGENT);
        unsigned a2 = __hip_atomic_load(&flags[(lane + 128) * FLAG_STRIDE], __ATOMIC_RELAXED, __HIP_MEMORY_SCOPE_AGENT);
        unsigned a3 = __hip_atomic_load(&flags[(lane + 192) * FLAG_STRIDE], __ATOMIC_RELAXED, __HIP_MEMORY_SCOPE_AGENT);
        if (__all((a0 >= tgt) && (a1 >= tgt) && (a2 >= tgt) && (a3 >= tgt))) break;
        __builtin_amdgcn_s_sleep(1);
      }
      __builtin_amdgcn_fence(__ATOMIC_ACQUIRE, "agent");
    }
  }
  D[gb * NH_D + j0 + gj] = creg;
}

extern "C" void kernel_launch(void* const* d_in, const int* in_sizes, int n_in,
                              void* d_out, int out_size, void* d_ws, size_t ws_size,
                              hipStream_t stream) {
  const float* X     = (const float*)d_in[0];
  const float* imask = (const float*)d_in[1];
  const float* h0    = (const float*)d_in[2];
  const float* c0    = (const float*)d_in[3];
  const float* Win   = (const float*)d_in[4];
  const float* Wre   = (const float*)d_in[5];
  const float* bias  = (const float*)d_in[6];
  float* out = (float*)d_out;

  char* ws = (char*)d_ws;
  unsigned short* Xbf    = (unsigned short*)(ws);                         // 64 MB (dead after gemm)
  unsigned short* WinT   = (unsigned short*)(ws + 67108864);              // 8 MB
  unsigned short* WreT   = (unsigned short*)(ws + 75497472);              // 8 MB
  unsigned short* intern = (unsigned short*)(ws + 83886080);              // 256 MB
  unsigned short* hbuf   = (unsigned short*)(ws + 352321536);             // 64 KB
  unsigned*       flags  = (unsigned*)(ws);                               // overlaid on Xbf (init after gemm)

  float* Y = out;
  float* C = out + (size_t)T_STEPS * BATCH * NH_D;
  float* D = out + (size_t)2 * T_STEPS * BATCH * NH_D;

  {
    int n4 = (MROWS * NIN_D) / 4;
    cast_f32_bf16<<<dim3((n4 + 255) / 256), dim3(256), 0, stream>>>(X, Xbf, n4);
  }
  transpose_cast<<<dim3(G_D / 32, NIN_D / 32), dim3(32, 8), 0, stream>>>(Win, WinT);
  transpose_cast<<<dim3(G_D / 32, NH_D / 32),  dim3(32, 8), 0, stream>>>(Wre, WreT);

  gemm_intern<<<dim3(G_D / 128, MROWS / 128), dim3(256), 0, stream>>>(Xbf, WinT, bias, intern);

  // flags overlay the Xbf region; init AFTER gemm (Xbf no longer needed)
  init_state<<<dim3((BATCH * NH_D + 255) / 256), dim3(256), 0, stream>>>(h0, hbuf, flags);

  lstm_scan<<<dim3(NBLK), dim3(64), 0, stream>>>(intern, WreT, imask, c0, hbuf, flags, Y, C, D);
}

// Round 3
// 10248.280 us; speedup vs baseline: 4.9214x; 2.3748x over previous
//
#include <hip/hip_runtime.h>
#include <cstdint>
#include <cstddef>

#define T_STEPS 2048
#define BATCH   16
#define NIN_D   1024
#define NH_D    1024
#define G_D     4096
#define MROWS   32768   // T*B
#define NWG     32      // scan workgroups
#define WGT     512     // threads per scan wg (8 waves)
#define FLAG_STRIDE 16  // dwords -> 64B padding per flag

typedef short short8 __attribute__((ext_vector_type(8)));
typedef float f32x4  __attribute__((ext_vector_type(4)));

__device__ __forceinline__ unsigned short f2bf(float f) {
  unsigned u = __builtin_bit_cast(unsigned, f);
  u += 0x7FFFu + ((u >> 16) & 1u);          // RNE
  return (unsigned short)(u >> 16);
}
__device__ __forceinline__ float bf2f(unsigned short h) {
  unsigned u = ((unsigned)h) << 16;
  return __builtin_bit_cast(float, u);
}
__device__ __forceinline__ float sigmoidf_(float x) { return 1.0f / (1.0f + __expf(-x)); }
__device__ __forceinline__ float tanhf_(float x)    { return 2.0f / (1.0f + __expf(-2.0f * x)) - 1.0f; }

// ---------------- cast X: f32 -> bf16, vectorized ----------------
__global__ void cast_f32_bf16(const float* __restrict__ in, unsigned short* __restrict__ out, int n4) {
  int idx = blockIdx.x * blockDim.x + threadIdx.x;
  if (idx < n4) {
    float4 v = ((const float4*)in)[idx];
    ushort4 o;
    o.x = f2bf(v.x); o.y = f2bf(v.y); o.z = f2bf(v.z); o.w = f2bf(v.w);
    ((ushort4*)out)[idx] = o;
  }
}

// ---------------- transpose+cast W [1024][4096] f32 -> WT [4096][1024] bf16 ----------------
__global__ void transpose_cast(const float* __restrict__ in, unsigned short* __restrict__ out) {
  __shared__ float tile[32][33];
  const int gx = blockIdx.x * 32;
  const int gy = blockIdx.y * 32;
  const int tx = threadIdx.x, ty = threadIdx.y;   // (32,8)
  #pragma unroll
  for (int p = 0; p < 4; ++p)
    tile[ty + p * 8][tx] = in[(size_t)(gy + ty + p * 8) * G_D + gx + tx];
  __syncthreads();
  #pragma unroll
  for (int p = 0; p < 4; ++p)
    out[(size_t)(gx + ty + p * 8) * NIN_D + gy + tx] = f2bf(tile[tx][ty + p * 8]);
}

// ---------------- init: zero flags, hbuf[0] = bf16(h0) ----------------
__global__ void init_state(const float* __restrict__ h0, unsigned short* __restrict__ hbuf,
                           unsigned* __restrict__ flags) {
  int idx = blockIdx.x * blockDim.x + threadIdx.x;
  if (idx < NWG * FLAG_STRIDE) flags[idx] = 0u;
  if (idx < BATCH * NH_D) hbuf[idx] = f2bf(h0[idx]);
}

// ---------------- intern GEMM: C[m][g] = A[m][:] . BT[g][:] + bias[g] (bf16 out) ----------------
__global__ __launch_bounds__(256) void gemm_intern(
    const unsigned short* __restrict__ A,
    const unsigned short* __restrict__ Bt,
    const float* __restrict__ bias,
    unsigned short* __restrict__ Out) {
  __shared__ unsigned short As[128 * 72];
  __shared__ unsigned short Bs[128 * 72];
  const int tid  = threadIdx.x;
  const int lane = tid & 63;
  const int w    = tid >> 6;
  const int r16  = lane & 15;
  const int kgrp = lane >> 4;
  const int wrow = (w >> 1) * 64;
  const int wcol = (w & 1) * 64;
  const int bx = blockIdx.x;
  const int by = blockIdx.y;

  const unsigned short* Ag = A  + (size_t)by * 128 * NIN_D;
  const unsigned short* Bg = Bt + (size_t)bx * 128 * NIN_D;
  const int trow = tid >> 3;
  const int tcol = (tid & 7) * 8;

  f32x4 acc[4][4];
  #pragma unroll
  for (int m = 0; m < 4; ++m)
    #pragma unroll
    for (int n = 0; n < 4; ++n)
      acc[m][n] = (f32x4){0.f, 0.f, 0.f, 0.f};

  for (int kt = 0; kt < 16; ++kt) {
    const int kb = kt * 64;
    __syncthreads();
    #pragma unroll
    for (int p = 0; p < 4; ++p) {
      const int r = trow + p * 32;
      *(uint4*)(&As[r * 72 + tcol]) = *(const uint4*)(Ag + (size_t)r * NIN_D + kb + tcol);
      *(uint4*)(&Bs[r * 72 + tcol]) = *(const uint4*)(Bg + (size_t)r * NIN_D + kb + tcol);
    }
    __syncthreads();
    #pragma unroll
    for (int kk = 0; kk < 2; ++kk) {
      const int ko = kk * 32 + kgrp * 8;
      short8 af[4], bq[4];
      #pragma unroll
      for (int m = 0; m < 4; ++m)
        af[m] = *(const short8*)(&As[(wrow + m * 16 + r16) * 72 + ko]);
      #pragma unroll
      for (int n = 0; n < 4; ++n)
        bq[n] = *(const short8*)(&Bs[(wcol + n * 16 + r16) * 72 + ko]);
      #pragma unroll
      for (int m = 0; m < 4; ++m)
        #pragma unroll
        for (int n = 0; n < 4; ++n)
          acc[m][n] = __builtin_amdgcn_mfma_f32_16x16x32_bf16(af[m], bq[n], acc[m][n], 0, 0, 0);
    }
  }
  #pragma unroll
  for (int n = 0; n < 4; ++n) {
    const int col = bx * 128 + wcol + n * 16 + r16;
    const float bv = bias[col];
    #pragma unroll
    for (int m = 0; m < 4; ++m) {
      const int row0 = by * 128 + wrow + m * 16 + kgrp * 4;
      #pragma unroll
      for (int i = 0; i < 4; ++i)
        Out[(size_t)(row0 + i) * G_D + col] = f2bf(acc[m][n][i] + bv);
    }
  }
}

// ---------------- persistent LSTM scan ----------------
// 32 wgs x 512 threads (8 waves). wg owns 32 hidden units (j0..j0+31) = 128 gate cols.
// Wave wv = hh*4+q computes gate q for j-half hh (16 cols) via 16x16x1024 MFMA chain.
// W_re fragments live in REGISTERS (128 VGPR/lane). h exchanged through MALL via
// relaxed agent-scope atomics (write-through) -- no cache-wide fences anywhere.
__global__ __launch_bounds__(WGT, 2) void lstm_scan(
    const unsigned short* __restrict__ intern, // [32768][4096] bf16
    const unsigned short* __restrict__ WreT,   // [4096][1024] bf16
    const float* __restrict__ msk,             // [2048][16]
    const float* __restrict__ c0,              // [16][1024]
    unsigned short* __restrict__ hbuf,         // [2][16][1024] bf16
    unsigned* __restrict__ flags,              // [NWG*FLAG_STRIDE]
    float* __restrict__ Y, float* __restrict__ C, float* __restrict__ D) {
  const int wg = blockIdx.x;
  const int tid = threadIdx.x;
  const int wv = tid >> 6, lane = tid & 63;
  const int r16 = lane & 15, kgrp = lane >> 4;
  const int q = wv & 3, hh = wv >> 2;
  const int j0 = wg * 32;

  __shared__ unsigned short h_s[16 * 1032];   // h tile, stride 1032 (2-way banks)
  __shared__ float z_s[8 * 16 * 17];          // per-wave 16x16 z tiles, padded

  // ---- W_re B-fragments into registers (once) ----
  short8 wfrag[32];
  {
    const unsigned short* wp = WreT + (size_t)(q * NH_D + j0 + hh * 16 + r16) * NH_D + kgrp * 8;
    #pragma unroll
    for (int kc = 0; kc < 32; ++kc)
      wfrag[kc] = *(const short8*)(wp + kc * 32);
  }

  // ---- gate-thread mapping ----
  const int b = tid >> 5, jj = tid & 31;
  float creg = c0[b * NH_D + j0 + jj];
  float mreg = msk[b];
  unsigned short ipr[4];
  #pragma unroll
  for (int qq = 0; qq < 4; ++qq)
    ipr[qq] = intern[(size_t)b * G_D + qq * NH_D + j0 + jj];

  // ---- stage h(0) into LDS ----
  {
    const unsigned long long* hb64 = (const unsigned long long*)hbuf;
    #pragma unroll
    for (int i = 0; i < 8; ++i) {
      unsigned long long v = __hip_atomic_load(&hb64[i * 512 + tid], __ATOMIC_RELAXED, __HIP_MEMORY_SCOPE_AGENT);
      const int u = i * 512 + tid;
      *(unsigned long long*)(&h_s[(u >> 8) * 1032 + (u & 255) * 4]) = v;
    }
  }
  __syncthreads();

  for (int t = 0; t < T_STEPS; ++t) {
    // ---- recurrent GEMM: z_tile = h @ Wre_cols (16x16, K=1024) ----
    f32x4 acc4[4];
    #pragma unroll
    for (int p = 0; p < 4; ++p) acc4[p] = (f32x4){0.f, 0.f, 0.f, 0.f};
    const int hrow = r16 * 1032;
    #pragma unroll
    for (int kc = 0; kc < 32; ++kc) {
      short8 a = *(const short8*)(&h_s[hrow + kc * 32 + kgrp * 8]);
      acc4[kc & 3] = __builtin_amdgcn_mfma_f32_16x16x32_bf16(a, wfrag[kc], acc4[kc & 3], 0, 0, 0);
    }
    f32x4 acc = (acc4[0] + acc4[1]) + (acc4[2] + acc4[3]);

    // stage z tile: C-frag rows are b = kgrp*4+i, col = r16
    #pragma unroll
    for (int i = 0; i < 4; ++i)
      z_s[(wv * 16 + kgrp * 4 + i) * 17 + r16] = acc[i];
    __syncthreads();

    // ---- gates (thread = (b, jj)) ----
    float zq[4];
    #pragma unroll
    for (int qq = 0; qq < 4; ++qq) {
      const int w2 = (jj >> 4) * 4 + qq;
      zq[qq] = z_s[(w2 * 16 + b) * 17 + (jj & 15)] + bf2f(ipr[qq]);
    }
    const float cell = tanhf_(zq[0]);
    const float ig = sigmoidf_(zq[1]);
    const float fg = sigmoidf_(zq[2]);
    const float og = sigmoidf_(zq[3]);
    const float cn = fg * creg + ig * cell;
    const float yn = og * tanhf_(cn);
    const float cnew = mreg * cn + (1.0f - mreg) * creg;
    const float ynew = mreg * yn;
    creg = cnew;

    // ---- publish h(t+1): packed u32 write-through atomics ----
    const unsigned short yb = f2bf(ynew);
    const unsigned partner = (unsigned)__shfl_xor((int)(unsigned)yb, 1);
    if ((tid & 1) == 0) {
      unsigned packed = ((unsigned)yb) | (partner << 16);
      unsigned* hn32 = (unsigned*)(hbuf + (size_t)((t + 1) & 1) * (BATCH * NH_D));
      __hip_atomic_store(&hn32[(b * NH_D + j0 + jj) >> 1], packed,
                         __ATOMIC_RELAXED, __HIP_MEMORY_SCOPE_AGENT);
    }
    asm volatile("s_waitcnt vmcnt(0)" ::: "memory");   // h stores acked at coherence point
    __syncthreads();                                   // all threads' h done
    if (tid == 0)
      __hip_atomic_store(&flags[wg * FLAG_STRIDE], (unsigned)(t + 1),
                         __ATOMIC_RELAXED, __HIP_MEMORY_SCOPE_AGENT);

    // ---- off-critical-path: outputs + next-step prefetch ----
    const size_t ob = ((size_t)t * BATCH + b) * NH_D + j0 + jj;
    __builtin_nontemporal_store(ynew, &Y[ob]);
    __builtin_nontemporal_store(cnew, &C[ob]);
    if (t < T_STEPS - 1) {
      const unsigned short* ipn = intern + ((size_t)(t + 1) * BATCH + b) * G_D;
      #pragma unroll
      for (int qq = 0; qq < 4; ++qq)
        ipr[qq] = ipn[qq * NH_D + j0 + jj];
      mreg = msk[(t + 1) * BATCH + b];

      // ---- barrier: wave 0 polls 32 flags (one lane each) ----
      if (wv == 0) {
        const unsigned tgt = (unsigned)(t + 1);
        for (;;) {
          unsigned f = tgt;
          if (lane < NWG)
            f = __hip_atomic_load(&flags[lane * FLAG_STRIDE], __ATOMIC_RELAXED, __HIP_MEMORY_SCOPE_AGENT);
          if (__all(f >= tgt)) break;
          __builtin_amdgcn_s_sleep(2);
        }
      }
      __syncthreads();

      // ---- stage h(t+1) into LDS (fresh from MALL) ----
      const unsigned long long* hb64 =
          (const unsigned long long*)(hbuf + (size_t)((t + 1) & 1) * (BATCH * NH_D));
      #pragma unroll
      for (int i = 0; i < 8; ++i) {
        unsigned long long v = __hip_atomic_load(&hb64[i * 512 + tid], __ATOMIC_RELAXED, __HIP_MEMORY_SCOPE_AGENT);
        const int u = i * 512 + tid;
        *(unsigned long long*)(&h_s[(u >> 8) * 1032 + (u & 255) * 4]) = v;
      }
      __syncthreads();
    }
  }
  D[b * NH_D + j0 + jj] = creg;
}

extern "C" void kernel_launch(void* const* d_in, const int* in_sizes, int n_in,
                              void* d_out, int out_size, void* d_ws, size_t ws_size,
                              hipStream_t stream) {
  const float* X     = (const float*)d_in[0];
  const float* imask = (const float*)d_in[1];
  const float* h0    = (const float*)d_in[2];
  const float* c0    = (const float*)d_in[3];
  const float* Win   = (const float*)d_in[4];
  const float* Wre   = (const float*)d_in[5];
  const float* bias  = (const float*)d_in[6];
  float* out = (float*)d_out;

  char* ws = (char*)d_ws;
  unsigned short* Xbf    = (unsigned short*)(ws);                         // 64 MB (dead after gemm)
  unsigned short* WinT   = (unsigned short*)(ws + 67108864);              // 8 MB
  unsigned short* WreT   = (unsigned short*)(ws + 75497472);              // 8 MB
  unsigned short* intern = (unsigned short*)(ws + 83886080);              // 256 MB
  unsigned short* hbuf   = (unsigned short*)(ws + 352321536);             // 64 KB
  unsigned*       flags  = (unsigned*)(ws + 352387072);                   // 2 KB

  float* Y = out;
  float* C = out + (size_t)T_STEPS * BATCH * NH_D;
  float* D = out + (size_t)2 * T_STEPS * BATCH * NH_D;

  {
    int n4 = (MROWS * NIN_D) / 4;
    cast_f32_bf16<<<dim3((n4 + 255) / 256), dim3(256), 0, stream>>>(X, Xbf, n4);
  }
  transpose_cast<<<dim3(G_D / 32, NIN_D / 32), dim3(32, 8), 0, stream>>>(Win, WinT);
  transpose_cast<<<dim3(G_D / 32, NH_D / 32),  dim3(32, 8), 0, stream>>>(Wre, WreT);
  init_state<<<dim3(64), dim3(256), 0, stream>>>(h0, hbuf, flags);

  gemm_intern<<<dim3(G_D / 128, MROWS / 128), dim3(256), 0, stream>>>(Xbf, WinT, bias, intern);

  lstm_scan<<<dim3(NWG), dim3(WGT), 0, stream>>>(intern, WreT, imask, c0, hbuf, flags, Y, C, D);
}

// Round 4
// 8560.408 us; speedup vs baseline: 5.8918x; 1.1972x over previous
//
#include <hip/hip_runtime.h>
#include <cstdint>
#include <cstddef>

#define T_STEPS 2048
#define BATCH   16
#define NIN_D   1024
#define NH_D    1024
#define G_D     4096
#define MROWS   32768   // T*B
#define NWG     32      // scan workgroups
#define WGT     512     // threads per scan wg (8 waves)
#define HWORDS  (BATCH * NH_D)   // 16384 tagged h words per buffer

typedef short short8 __attribute__((ext_vector_type(8)));
typedef float f32x4  __attribute__((ext_vector_type(4)));
typedef unsigned u32x4 __attribute__((ext_vector_type(4)));
typedef unsigned u32x2 __attribute__((ext_vector_type(2)));

__device__ __forceinline__ unsigned short f2bf(float f) {
  unsigned u = __builtin_bit_cast(unsigned, f);
  u += 0x7FFFu + ((u >> 16) & 1u);          // RNE
  return (unsigned short)(u >> 16);
}
__device__ __forceinline__ float bf2f(unsigned short h) {
  unsigned u = ((unsigned)h) << 16;
  return __builtin_bit_cast(float, u);
}
__device__ __forceinline__ float sigmoidf_(float x) { return 1.0f / (1.0f + __expf(-x)); }
__device__ __forceinline__ float tanhf_(float x)    { return 2.0f / (1.0f + __expf(-2.0f * x)) - 1.0f; }

// ---------------- cast X: f32 -> bf16, vectorized ----------------
__global__ void cast_f32_bf16(const float* __restrict__ in, unsigned short* __restrict__ out, int n4) {
  int idx = blockIdx.x * blockDim.x + threadIdx.x;
  if (idx < n4) {
    float4 v = ((const float4*)in)[idx];
    ushort4 o;
    o.x = f2bf(v.x); o.y = f2bf(v.y); o.z = f2bf(v.z); o.w = f2bf(v.w);
    ((ushort4*)out)[idx] = o;
  }
}

// ---------------- transpose+cast W [1024][4096] f32 -> WT [4096][1024] bf16 ----------------
__global__ void transpose_cast(const float* __restrict__ in, unsigned short* __restrict__ out) {
  __shared__ float tile[32][33];
  const int gx = blockIdx.x * 32;
  const int gy = blockIdx.y * 32;
  const int tx = threadIdx.x, ty = threadIdx.y;   // (32,8)
  #pragma unroll
  for (int p = 0; p < 4; ++p)
    tile[ty + p * 8][tx] = in[(size_t)(gy + ty + p * 8) * G_D + gx + tx];
  __syncthreads();
  #pragma unroll
  for (int p = 0; p < 4; ++p)
    out[(size_t)(gx + ty + p * 8) * NIN_D + gy + tx] = f2bf(tile[tx][ty + p * 8]);
}

// ---------------- init: buffer0 = tag0|bf16(h0), buffer1 = tag0 (never matches odd tags) ----------------
// Runs every launch -> resets tags between graph replays (determinism).
__global__ void init_state(const float* __restrict__ h0, unsigned* __restrict__ hw) {
  int idx = blockIdx.x * blockDim.x + threadIdx.x;
  if (idx < HWORDS) {
    hw[idx] = (unsigned)f2bf(h0[idx]);
    hw[HWORDS + idx] = 0u;
  }
}

// ---------------- intern GEMM: C[m][g] = A[m][:] . BT[g][:] + bias[g] (bf16 out) ----------------
__global__ __launch_bounds__(256) void gemm_intern(
    const unsigned short* __restrict__ A,
    const unsigned short* __restrict__ Bt,
    const float* __restrict__ bias,
    unsigned short* __restrict__ Out) {
  __shared__ unsigned short As[128 * 72];
  __shared__ unsigned short Bs[128 * 72];
  const int tid  = threadIdx.x;
  const int lane = tid & 63;
  const int w    = tid >> 6;
  const int r16  = lane & 15;
  const int kgrp = lane >> 4;
  const int wrow = (w >> 1) * 64;
  const int wcol = (w & 1) * 64;
  const int bx = blockIdx.x;
  const int by = blockIdx.y;

  const unsigned short* Ag = A  + (size_t)by * 128 * NIN_D;
  const unsigned short* Bg = Bt + (size_t)bx * 128 * NIN_D;
  const int trow = tid >> 3;
  const int tcol = (tid & 7) * 8;

  f32x4 acc[4][4];
  #pragma unroll
  for (int m = 0; m < 4; ++m)
    #pragma unroll
    for (int n = 0; n < 4; ++n)
      acc[m][n] = (f32x4){0.f, 0.f, 0.f, 0.f};

  for (int kt = 0; kt < 16; ++kt) {
    const int kb = kt * 64;
    __syncthreads();
    #pragma unroll
    for (int p = 0; p < 4; ++p) {
      const int r = trow + p * 32;
      *(uint4*)(&As[r * 72 + tcol]) = *(const uint4*)(Ag + (size_t)r * NIN_D + kb + tcol);
      *(uint4*)(&Bs[r * 72 + tcol]) = *(const uint4*)(Bg + (size_t)r * NIN_D + kb + tcol);
    }
    __syncthreads();
    #pragma unroll
    for (int kk = 0; kk < 2; ++kk) {
      const int ko = kk * 32 + kgrp * 8;
      short8 af[4], bq[4];
      #pragma unroll
      for (int m = 0; m < 4; ++m)
        af[m] = *(const short8*)(&As[(wrow + m * 16 + r16) * 72 + ko]);
      #pragma unroll
      for (int n = 0; n < 4; ++n)
        bq[n] = *(const short8*)(&Bs[(wcol + n * 16 + r16) * 72 + ko]);
      #pragma unroll
      for (int m = 0; m < 4; ++m)
        #pragma unroll
        for (int n = 0; n < 4; ++n)
          acc[m][n] = __builtin_amdgcn_mfma_f32_16x16x32_bf16(af[m], bq[n], acc[m][n], 0, 0, 0);
    }
  }
  #pragma unroll
  for (int n = 0; n < 4; ++n) {
    const int col = bx * 128 + wcol + n * 16 + r16;
    const float bv = bias[col];
    #pragma unroll
    for (int m = 0; m < 4; ++m) {
      const int row0 = by * 128 + wrow + m * 16 + kgrp * 4;
      #pragma unroll
      for (int i = 0; i < 4; ++i)
        Out[(size_t)(row0 + i) * G_D + col] = f2bf(acc[m][n][i] + bv);
    }
  }
}

// ---------------- tagged-word poll + LDS stage ----------------
// Thread owns 8 dwordx4 quads: quad i = words 4*(i*WGT+tid)..+3 of the 16384-word
// h buffer. Loads bypass L1/L2 (sc0 sc1) and hit the device coherence point.
// Each u32 = {tag:16 | bf16:16}; per-word consistency is intrinsic to the load.
__device__ __forceinline__ void poll_stage(const unsigned* __restrict__ buf, unsigned tgt,
                                           int tid, unsigned short* __restrict__ h_s) {
  u32x4 q0, q1, q2, q3, q4, q5, q6, q7;
  const unsigned* p0 = buf + (0 * WGT + tid) * 4;
  const unsigned* p1 = buf + (1 * WGT + tid) * 4;
  const unsigned* p2 = buf + (2 * WGT + tid) * 4;
  const unsigned* p3 = buf + (3 * WGT + tid) * 4;
  const unsigned* p4 = buf + (4 * WGT + tid) * 4;
  const unsigned* p5 = buf + (5 * WGT + tid) * 4;
  const unsigned* p6 = buf + (6 * WGT + tid) * 4;
  const unsigned* p7 = buf + (7 * WGT + tid) * 4;
  bool done = false;
  do {
    if (!done) {
      asm volatile(
          "global_load_dwordx4 %0, %8, off sc0 sc1\n\t"
          "global_load_dwordx4 %1, %9, off sc0 sc1\n\t"
          "global_load_dwordx4 %2, %10, off sc0 sc1\n\t"
          "global_load_dwordx4 %3, %11, off sc0 sc1\n\t"
          "global_load_dwordx4 %4, %12, off sc0 sc1\n\t"
          "global_load_dwordx4 %5, %13, off sc0 sc1\n\t"
          "global_load_dwordx4 %6, %14, off sc0 sc1\n\t"
          "global_load_dwordx4 %7, %15, off sc0 sc1\n\t"
          "s_waitcnt vmcnt(0)"
          : "=v"(q0), "=v"(q1), "=v"(q2), "=v"(q3),
            "=v"(q4), "=v"(q5), "=v"(q6), "=v"(q7)
          : "v"(p0), "v"(p1), "v"(p2), "v"(p3),
            "v"(p4), "v"(p5), "v"(p6), "v"(p7)
          : "memory");
      done = (q0[0] >> 16) == tgt && (q0[1] >> 16) == tgt && (q0[2] >> 16) == tgt && (q0[3] >> 16) == tgt
          && (q1[0] >> 16) == tgt && (q1[1] >> 16) == tgt && (q1[2] >> 16) == tgt && (q1[3] >> 16) == tgt
          && (q2[0] >> 16) == tgt && (q2[1] >> 16) == tgt && (q2[2] >> 16) == tgt && (q2[3] >> 16) == tgt
          && (q3[0] >> 16) == tgt && (q3[1] >> 16) == tgt && (q3[2] >> 16) == tgt && (q3[3] >> 16) == tgt
          && (q4[0] >> 16) == tgt && (q4[1] >> 16) == tgt && (q4[2] >> 16) == tgt && (q4[3] >> 16) == tgt
          && (q5[0] >> 16) == tgt && (q5[1] >> 16) == tgt && (q5[2] >> 16) == tgt && (q5[3] >> 16) == tgt
          && (q6[0] >> 16) == tgt && (q6[1] >> 16) == tgt && (q6[2] >> 16) == tgt && (q6[3] >> 16) == tgt
          && (q7[0] >> 16) == tgt && (q7[1] >> 16) == tgt && (q7[2] >> 16) == tgt && (q7[3] >> 16) == tgt;
    }
  } while (!__all((int)done));
  // stage payloads into h_s (row = u>>10, col = u&1023, row stride 1032 shorts)
#define STG(i, Q) { \
    const int u_ = 4 * ((i) * WGT + tid); \
    u32x2 o_; \
    o_[0] = (Q[0] & 0xFFFFu) | (Q[1] << 16); \
    o_[1] = (Q[2] & 0xFFFFu) | (Q[3] << 16); \
    *(u32x2*)(h_s + ((u_ >> 10) * 1032 + (u_ & 1023))) = o_; }
  STG(0, q0) STG(1, q1) STG(2, q2) STG(3, q3)
  STG(4, q4) STG(5, q5) STG(6, q6) STG(7, q7)
#undef STG
}

// ---------------- persistent LSTM scan ----------------
// 32 wgs x 512 threads (8 waves). wg owns 32 hidden units = 128 gate cols.
// Wave wv = hh*4+q computes gate q for j-half hh via 16x16x1024 MFMA chain.
// Sync = tagged h-words only: no flags, no fences, no RMW atomics.
__global__ __launch_bounds__(WGT, 2) void lstm_scan(
    const unsigned short* __restrict__ intern, // [32768][4096] bf16
    const unsigned short* __restrict__ WreT,   // [4096][1024] bf16
    const float* __restrict__ msk,             // [2048][16]
    const float* __restrict__ c0,              // [16][1024]
    unsigned* __restrict__ hw,                 // [2][HWORDS] tagged u32
    float* __restrict__ Y, float* __restrict__ C, float* __restrict__ D) {
  const int wg = blockIdx.x;
  const int tid = threadIdx.x;
  const int wv = tid >> 6, lane = tid & 63;
  const int r16 = lane & 15, kgrp = lane >> 4;
  const int q = wv & 3, hh = wv >> 2;
  const int j0 = wg * 32;

  __shared__ unsigned short h_s[16 * 1032];   // h tile, stride 1032 (2-way banks on read)
  __shared__ float z_s[8 * 16 * 17];          // per-wave 16x16 z tiles, padded

  // ---- W_re B-fragments into registers (once) ----
  short8 wfrag[32];
  {
    const unsigned short* wp = WreT + (size_t)(q * NH_D + j0 + hh * 16 + r16) * NH_D + kgrp * 8;
    #pragma unroll
    for (int kc = 0; kc < 32; ++kc)
      wfrag[kc] = *(const short8*)(wp + kc * 32);
  }

  // ---- gate-thread mapping ----
  const int b = tid >> 5, jj = tid & 31;
  float creg = c0[b * NH_D + j0 + jj];
  float mreg = msk[b];
  unsigned short ipr[4];
  #pragma unroll
  for (int qq = 0; qq < 4; ++qq)
    ipr[qq] = intern[(size_t)b * G_D + qq * NH_D + j0 + jj];

  // ---- stage h(0): buffer0, tag 0 ----
  poll_stage(hw, 0u, tid, h_s);
  __syncthreads();

  for (int t = 0; t < T_STEPS; ++t) {
    // ---- recurrent GEMM: z_tile = h @ Wre_cols (16x16, K=1024) ----
    f32x4 acc4[4];
    #pragma unroll
    for (int p = 0; p < 4; ++p) acc4[p] = (f32x4){0.f, 0.f, 0.f, 0.f};
    const int hrow = r16 * 1032;
    #pragma unroll
    for (int kc = 0; kc < 32; ++kc) {
      short8 a = *(const short8*)(&h_s[hrow + kc * 32 + kgrp * 8]);
      acc4[kc & 3] = __builtin_amdgcn_mfma_f32_16x16x32_bf16(a, wfrag[kc], acc4[kc & 3], 0, 0, 0);
    }
    f32x4 acc = (acc4[0] + acc4[1]) + (acc4[2] + acc4[3]);

    // stage z tile: C-frag rows are b = kgrp*4+i, col = r16
    #pragma unroll
    for (int i = 0; i < 4; ++i)
      z_s[(wv * 16 + kgrp * 4 + i) * 17 + r16] = acc[i];
    __syncthreads();   // sync#1: z_s ready; also: all h_s reads for step t done

    // ---- gates (thread = (b, jj)) ----
    float zq[4];
    #pragma unroll
    for (int qq = 0; qq < 4; ++qq) {
      const int w2 = (jj >> 4) * 4 + qq;
      zq[qq] = z_s[(w2 * 16 + b) * 17 + (jj & 15)] + bf2f(ipr[qq]);
    }
    const float cell = tanhf_(zq[0]);
    const float ig = sigmoidf_(zq[1]);
    const float fg = sigmoidf_(zq[2]);
    const float og = sigmoidf_(zq[3]);
    const float cn = fg * creg + ig * cell;
    const float yn = og * tanhf_(cn);
    const float cnew = mreg * cn + (1.0f - mreg) * creg;
    const float ynew = mreg * yn;
    creg = cnew;

    // ---- publish h(t+1): one self-describing tagged store, fire-and-forget ----
    if (t < T_STEPS - 1) {
      unsigned* dst = hw + (size_t)((t + 1) & 1) * HWORDS;
      __hip_atomic_store(&dst[b * NH_D + j0 + jj],
                         (((unsigned)(t + 1)) << 16) | (unsigned)f2bf(ynew),
                         __ATOMIC_RELAXED, __HIP_MEMORY_SCOPE_AGENT);
    }

    // ---- off-critical-path: outputs + next-step prefetch ----
    const size_t ob = ((size_t)t * BATCH + b) * NH_D + j0 + jj;
    __builtin_nontemporal_store(ynew, &Y[ob]);
    __builtin_nontemporal_store(cnew, &C[ob]);

    if (t < T_STEPS - 1) {
      const unsigned short* ipn = intern + ((size_t)(t + 1) * BATCH + b) * G_D;
      #pragma unroll
      for (int qq = 0; qq < 4; ++qq)
        ipr[qq] = ipn[qq * NH_D + j0 + jj];
      mreg = msk[(t + 1) * BATCH + b];

      // ---- poll tagged words for step t+1 and stage into h_s ----
      poll_stage(hw + (size_t)((t + 1) & 1) * HWORDS, (unsigned)(t + 1), tid, h_s);
    }
    __syncthreads();   // sync#2: h_s(t+1) staged before next MFMA
  }
  D[b * NH_D + j0 + jj] = creg;
}

extern "C" void kernel_launch(void* const* d_in, const int* in_sizes, int n_in,
                              void* d_out, int out_size, void* d_ws, size_t ws_size,
                              hipStream_t stream) {
  const float* X     = (const float*)d_in[0];
  const float* imask = (const float*)d_in[1];
  const float* h0    = (const float*)d_in[2];
  const float* c0    = (const float*)d_in[3];
  const float* Win   = (const float*)d_in[4];
  const float* Wre   = (const float*)d_in[5];
  const float* bias  = (const float*)d_in[6];
  float* out = (float*)d_out;

  char* ws = (char*)d_ws;
  unsigned short* Xbf    = (unsigned short*)(ws);                         // 64 MB (dead after gemm)
  unsigned short* WinT   = (unsigned short*)(ws + 67108864);              // 8 MB
  unsigned short* WreT   = (unsigned short*)(ws + 75497472);              // 8 MB
  unsigned short* intern = (unsigned short*)(ws + 83886080);              // 256 MB
  unsigned*       hw     = (unsigned*)(ws);                               // 128 KB tagged h, overlays Xbf

  float* Y = out;
  float* C = out + (size_t)T_STEPS * BATCH * NH_D;
  float* D = out + (size_t)2 * T_STEPS * BATCH * NH_D;

  {
    int n4 = (MROWS * NIN_D) / 4;
    cast_f32_bf16<<<dim3((n4 + 255) / 256), dim3(256), 0, stream>>>(X, Xbf, n4);
  }
  transpose_cast<<<dim3(G_D / 32, NIN_D / 32), dim3(32, 8), 0, stream>>>(Win, WinT);
  transpose_cast<<<dim3(G_D / 32, NH_D / 32),  dim3(32, 8), 0, stream>>>(Wre, WreT);

  gemm_intern<<<dim3(G_D / 128, MROWS / 128), dim3(256), 0, stream>>>(Xbf, WinT, bias, intern);

  // hw overlays the (now dead) Xbf region; reset tags AFTER gemm, every launch
  init_state<<<dim3(64), dim3(256), 0, stream>>>(h0, hw);

  lstm_scan<<<dim3(NWG), dim3(WGT), 0, stream>>>(intern, WreT, imask, c0, hw, Y, C, D);
}

// Round 5
// 7622.293 us; speedup vs baseline: 6.6169x; 1.1231x over previous
//
#include <hip/hip_runtime.h>
#include <cstdint>
#include <cstddef>

#define T_STEPS 2048
#define BATCH   16
#define NIN_D   1024
#define NH_D    1024
#define G_D     4096
#define MROWS   32768   // T*B
#define NWG     64      // scan workgroups
#define WGT     512     // threads per scan wg (8 waves)
#define HWORDS  (BATCH * NH_D)   // 16384 tagged h words per buffer

typedef short short8 __attribute__((ext_vector_type(8)));
typedef float f32x4  __attribute__((ext_vector_type(4)));
typedef unsigned u32x4 __attribute__((ext_vector_type(4)));
typedef unsigned u32x2 __attribute__((ext_vector_type(2)));

__device__ __forceinline__ unsigned short f2bf(float f) {
  unsigned u = __builtin_bit_cast(unsigned, f);
  u += 0x7FFFu + ((u >> 16) & 1u);          // RNE
  return (unsigned short)(u >> 16);
}
__device__ __forceinline__ float bf2f(unsigned short h) {
  unsigned u = ((unsigned)h) << 16;
  return __builtin_bit_cast(float, u);
}
__device__ __forceinline__ float sigmoidf_(float x) { return 1.0f / (1.0f + __expf(-x)); }
__device__ __forceinline__ float tanhf_(float x)    { return 2.0f / (1.0f + __expf(-2.0f * x)) - 1.0f; }

// ---------------- cast X: f32 -> bf16, vectorized ----------------
__global__ void cast_f32_bf16(const float* __restrict__ in, unsigned short* __restrict__ out, int n4) {
  int idx = blockIdx.x * blockDim.x + threadIdx.x;
  if (idx < n4) {
    float4 v = ((const float4*)in)[idx];
    ushort4 o;
    o.x = f2bf(v.x); o.y = f2bf(v.y); o.z = f2bf(v.z); o.w = f2bf(v.w);
    ((ushort4*)out)[idx] = o;
  }
}

// ---------------- transpose+cast W [1024][4096] f32 -> WT [4096][1024] bf16 ----------------
__global__ void transpose_cast(const float* __restrict__ in, unsigned short* __restrict__ out) {
  __shared__ float tile[32][33];
  const int gx = blockIdx.x * 32;
  const int gy = blockIdx.y * 32;
  const int tx = threadIdx.x, ty = threadIdx.y;   // (32,8)
  #pragma unroll
  for (int p = 0; p < 4; ++p)
    tile[ty + p * 8][tx] = in[(size_t)(gy + ty + p * 8) * G_D + gx + tx];
  __syncthreads();
  #pragma unroll
  for (int p = 0; p < 4; ++p)
    out[(size_t)(gx + ty + p * 8) * NIN_D + gy + tx] = f2bf(tile[tx][ty + p * 8]);
}

// ---------------- init: buffer0 = tag0|bf16(h0), buffer1 = tag0 (never matches odd tags) ----------------
__global__ void init_state(const float* __restrict__ h0, unsigned* __restrict__ hw) {
  int idx = blockIdx.x * blockDim.x + threadIdx.x;
  if (idx < HWORDS) {
    hw[idx] = (unsigned)f2bf(h0[idx]);
    hw[HWORDS + idx] = 0u;
  }
}

// ---------------- intern GEMM: C[m][g] = A[m][:] . BT[g][:] + bias[g] (bf16 out) ----------------
__global__ __launch_bounds__(256) void gemm_intern(
    const unsigned short* __restrict__ A,
    const unsigned short* __restrict__ Bt,
    const float* __restrict__ bias,
    unsigned short* __restrict__ Out) {
  __shared__ unsigned short As[128 * 72];
  __shared__ unsigned short Bs[128 * 72];
  const int tid  = threadIdx.x;
  const int lane = tid & 63;
  const int w    = tid >> 6;
  const int r16  = lane & 15;
  const int kgrp = lane >> 4;
  const int wrow = (w >> 1) * 64;
  const int wcol = (w & 1) * 64;
  const int bx = blockIdx.x;
  const int by = blockIdx.y;

  const unsigned short* Ag = A  + (size_t)by * 128 * NIN_D;
  const unsigned short* Bg = Bt + (size_t)bx * 128 * NIN_D;
  const int trow = tid >> 3;
  const int tcol = (tid & 7) * 8;

  f32x4 acc[4][4];
  #pragma unroll
  for (int m = 0; m < 4; ++m)
    #pragma unroll
    for (int n = 0; n < 4; ++n)
      acc[m][n] = (f32x4){0.f, 0.f, 0.f, 0.f};

  for (int kt = 0; kt < 16; ++kt) {
    const int kb = kt * 64;
    __syncthreads();
    #pragma unroll
    for (int p = 0; p < 4; ++p) {
      const int r = trow + p * 32;
      *(uint4*)(&As[r * 72 + tcol]) = *(const uint4*)(Ag + (size_t)r * NIN_D + kb + tcol);
      *(uint4*)(&Bs[r * 72 + tcol]) = *(const uint4*)(Bg + (size_t)r * NIN_D + kb + tcol);
    }
    __syncthreads();
    #pragma unroll
    for (int kk = 0; kk < 2; ++kk) {
      const int ko = kk * 32 + kgrp * 8;
      short8 af[4], bq[4];
      #pragma unroll
      for (int m = 0; m < 4; ++m)
        af[m] = *(const short8*)(&As[(wrow + m * 16 + r16) * 72 + ko]);
      #pragma unroll
      for (int n = 0; n < 4; ++n)
        bq[n] = *(const short8*)(&Bs[(wcol + n * 16 + r16) * 72 + ko]);
      #pragma unroll
      for (int m = 0; m < 4; ++m)
        #pragma unroll
        for (int n = 0; n < 4; ++n)
          acc[m][n] = __builtin_amdgcn_mfma_f32_16x16x32_bf16(af[m], bq[n], acc[m][n], 0, 0, 0);
    }
  }
  #pragma unroll
  for (int n = 0; n < 4; ++n) {
    const int col = bx * 128 + wcol + n * 16 + r16;
    const float bv = bias[col];
    #pragma unroll
    for (int m = 0; m < 4; ++m) {
      const int row0 = by * 128 + wrow + m * 16 + kgrp * 4;
      #pragma unroll
      for (int i = 0; i < 4; ++i)
        Out[(size_t)(row0 + i) * G_D + col] = f2bf(acc[m][n][i] + bv);
    }
  }
}

// ---------------- tagged-word poll + LDS stage ----------------
// Thread owns 8 dwordx4 quads covering the 16384-word h buffer. Loads bypass
// L1/L2 (sc0 sc1). Each u32 = {tag:16 | bf16:16}; per-word consistency is
// intrinsic to the 32-bit load granule. s_sleep(1) backoff on miss.
__device__ __forceinline__ void poll_stage(const unsigned* __restrict__ buf, unsigned tgt,
                                           int tid, unsigned short* __restrict__ h_s) {
  u32x4 q0, q1, q2, q3, q4, q5, q6, q7;
  const unsigned* p0 = buf + (0 * WGT + tid) * 4;
  const unsigned* p1 = buf + (1 * WGT + tid) * 4;
  const unsigned* p2 = buf + (2 * WGT + tid) * 4;
  const unsigned* p3 = buf + (3 * WGT + tid) * 4;
  const unsigned* p4 = buf + (4 * WGT + tid) * 4;
  const unsigned* p5 = buf + (5 * WGT + tid) * 4;
  const unsigned* p6 = buf + (6 * WGT + tid) * 4;
  const unsigned* p7 = buf + (7 * WGT + tid) * 4;
  bool done = false;
  bool first = true;
  do {
    if (!first && !done) __builtin_amdgcn_s_sleep(1);
    first = false;
    if (!done) {
      asm volatile(
          "global_load_dwordx4 %0, %8, off sc0 sc1\n\t"
          "global_load_dwordx4 %1, %9, off sc0 sc1\n\t"
          "global_load_dwordx4 %2, %10, off sc0 sc1\n\t"
          "global_load_dwordx4 %3, %11, off sc0 sc1\n\t"
          "global_load_dwordx4 %4, %12, off sc0 sc1\n\t"
          "global_load_dwordx4 %5, %13, off sc0 sc1\n\t"
          "global_load_dwordx4 %6, %14, off sc0 sc1\n\t"
          "global_load_dwordx4 %7, %15, off sc0 sc1\n\t"
          "s_waitcnt vmcnt(0)"
          : "=v"(q0), "=v"(q1), "=v"(q2), "=v"(q3),
            "=v"(q4), "=v"(q5), "=v"(q6), "=v"(q7)
          : "v"(p0), "v"(p1), "v"(p2), "v"(p3),
            "v"(p4), "v"(p5), "v"(p6), "v"(p7)
          : "memory");
      done = (q0[0] >> 16) == tgt && (q0[1] >> 16) == tgt && (q0[2] >> 16) == tgt && (q0[3] >> 16) == tgt
          && (q1[0] >> 16) == tgt && (q1[1] >> 16) == tgt && (q1[2] >> 16) == tgt && (q1[3] >> 16) == tgt
          && (q2[0] >> 16) == tgt && (q2[1] >> 16) == tgt && (q2[2] >> 16) == tgt && (q2[3] >> 16) == tgt
          && (q3[0] >> 16) == tgt && (q3[1] >> 16) == tgt && (q3[2] >> 16) == tgt && (q3[3] >> 16) == tgt
          && (q4[0] >> 16) == tgt && (q4[1] >> 16) == tgt && (q4[2] >> 16) == tgt && (q4[3] >> 16) == tgt
          && (q5[0] >> 16) == tgt && (q5[1] >> 16) == tgt && (q5[2] >> 16) == tgt && (q5[3] >> 16) == tgt
          && (q6[0] >> 16) == tgt && (q6[1] >> 16) == tgt && (q6[2] >> 16) == tgt && (q6[3] >> 16) == tgt
          && (q7[0] >> 16) == tgt && (q7[1] >> 16) == tgt && (q7[2] >> 16) == tgt && (q7[3] >> 16) == tgt;
    }
  } while (!__all((int)done));
  // stage payloads into h_s (row = u>>10 batch, col = u&1023 hidden; row stride 1032 shorts)
#define STG(i, Q) { \
    const int u_ = 4 * ((i) * WGT + tid); \
    u32x2 o_; \
    o_[0] = (Q[0] & 0xFFFFu) | (Q[1] << 16); \
    o_[1] = (Q[2] & 0xFFFFu) | (Q[3] << 16); \
    *(u32x2*)(h_s + ((u_ >> 10) * 1032 + (u_ & 1023))) = o_; }
  STG(0, q0) STG(1, q1) STG(2, q2) STG(3, q3)
  STG(4, q4) STG(5, q5) STG(6, q6) STG(7, q7)
#undef STG
}

// ---------------- persistent LSTM scan ----------------
// 64 wgs x 512 threads (8 waves). wg owns 16 hidden units (j0..j0+15) = 64 gate cols.
// Wave wv = (ks<<2)|q computes gate q over K-half ks (K=512): wfrag = 16 chunks (64 VGPR),
// 16 ds_read_b128 per wave per step (half of R4's per-CU LDS traffic, on 2x the CUs).
// Partial z tiles from the two K-halves reduce through z_s at the existing barrier.
// Sync = tagged h-words only: no flags, no fences, no RMW atomics.
__global__ __launch_bounds__(WGT, 2) void lstm_scan(
    const unsigned short* __restrict__ intern, // [32768][4096] bf16
    const unsigned short* __restrict__ WreT,   // [4096][1024] bf16
    const float* __restrict__ msk,             // [2048][16]
    const float* __restrict__ c0,              // [16][1024]
    unsigned* __restrict__ hw,                 // [2][HWORDS] tagged u32
    float* __restrict__ Y, float* __restrict__ C, float* __restrict__ D) {
  const int wg = blockIdx.x;
  const int tid = threadIdx.x;
  const int wv = tid >> 6, lane = tid & 63;
  const int r16 = lane & 15, kgrp = lane >> 4;
  const int q = wv & 3, ks = wv >> 2;
  const int j0 = wg * 16;

  __shared__ unsigned short h_s[16 * 1032];   // h tile, stride 1032 (bank-rotation optimal)
  __shared__ float z_s[8 * 16 * 17];          // 8 partial 16x16 z tiles, padded

  // ---- W_re B-fragments into registers (once): gate q, cols j0+r16, K-half ks ----
  short8 wfrag[16];
  {
    const unsigned short* wp = WreT + (size_t)(q * NH_D + j0 + r16) * NH_D + ks * 512 + kgrp * 8;
    #pragma unroll
    for (int kc = 0; kc < 16; ++kc)
      wfrag[kc] = *(const short8*)(wp + kc * 32);
  }

  // ---- gate-thread mapping: tid<256 -> (b = tid>>4, jj = tid&15) ----
  const int b = tid >> 4, jj = tid & 15;
  const bool gt = tid < 256;
  float creg = 0.f, mreg = 0.f;
  unsigned short ipr[4] = {0, 0, 0, 0};
  if (gt) {
    creg = c0[b * NH_D + j0 + jj];
    mreg = msk[b];
    #pragma unroll
    for (int qq = 0; qq < 4; ++qq)
      ipr[qq] = intern[(size_t)b * G_D + qq * NH_D + j0 + jj];
  }

  // ---- stage h(0): buffer0, tag 0 ----
  poll_stage(hw, 0u, tid, h_s);
  __syncthreads();

  for (int t = 0; t < T_STEPS; ++t) {
    // ---- recurrent GEMM: partial z tile = h[:, ks*512:+512] @ W-cols (16x16, K=512) ----
    f32x4 acc4[4];
    #pragma unroll
    for (int p = 0; p < 4; ++p) acc4[p] = (f32x4){0.f, 0.f, 0.f, 0.f};
    const int hbase = r16 * 1032 + ks * 512 + kgrp * 8;
    #pragma unroll
    for (int kc = 0; kc < 16; ++kc) {
      short8 a = *(const short8*)(&h_s[hbase + kc * 32]);
      acc4[kc & 3] = __builtin_amdgcn_mfma_f32_16x16x32_bf16(a, wfrag[kc], acc4[kc & 3], 0, 0, 0);
    }
    f32x4 acc = (acc4[0] + acc4[1]) + (acc4[2] + acc4[3]);

    // stage partial z tile: C-frag rows are b = kgrp*4+i, col = r16
    #pragma unroll
    for (int i = 0; i < 4; ++i)
      z_s[((wv)*16 + kgrp * 4 + i) * 17 + r16] = acc[i];
    __syncthreads();   // sync#1: z ready; all h_s reads for step t done

    if (gt) {
      // ---- gates (thread = (b, jj)): sum the two K-half partials ----
      float zq[4];
      #pragma unroll
      for (int qq = 0; qq < 4; ++qq)
        zq[qq] = z_s[((qq)*16 + b) * 17 + jj] + z_s[((4 + qq) * 16 + b) * 17 + jj] + bf2f(ipr[qq]);
      const float cell = tanhf_(zq[0]);
      const float ig = sigmoidf_(zq[1]);
      const float fg = sigmoidf_(zq[2]);
      const float og = sigmoidf_(zq[3]);
      const float cn = fg * creg + ig * cell;
      const float yn = og * tanhf_(cn);
      const float cnew = mreg * cn + (1.0f - mreg) * creg;
      const float ynew = mreg * yn;
      creg = cnew;

      // ---- publish h(t+1): one self-describing tagged store, fire-and-forget ----
      if (t < T_STEPS - 1) {
        unsigned* dst = hw + (size_t)((t + 1) & 1) * HWORDS;
        __hip_atomic_store(&dst[b * NH_D + j0 + jj],
                           (((unsigned)(t + 1)) << 16) | (unsigned)f2bf(ynew),
                           __ATOMIC_RELAXED, __HIP_MEMORY_SCOPE_AGENT);
      }

      // ---- off-critical-path: outputs + next-step operand prefetch ----
      const size_t ob = ((size_t)t * BATCH + b) * NH_D + j0 + jj;
      __builtin_nontemporal_store(ynew, &Y[ob]);
      __builtin_nontemporal_store(cnew, &C[ob]);
      if (t < T_STEPS - 1) {
        const unsigned short* ipn = intern + ((size_t)(t + 1) * BATCH + b) * G_D;
        #pragma unroll
        for (int qq = 0; qq < 4; ++qq)
          ipr[qq] = ipn[qq * NH_D + j0 + jj];
        mreg = msk[(t + 1) * BATCH + b];
      }
    }

    if (t < T_STEPS - 1)
      poll_stage(hw + (size_t)((t + 1) & 1) * HWORDS, (unsigned)(t + 1), tid, h_s);
    __syncthreads();   // sync#2: h_s(t+1) staged before next MFMA
  }
  if (gt) D[b * NH_D + j0 + jj] = creg;
}

extern "C" void kernel_launch(void* const* d_in, const int* in_sizes, int n_in,
                              void* d_out, int out_size, void* d_ws, size_t ws_size,
                              hipStream_t stream) {
  const float* X     = (const float*)d_in[0];
  const float* imask = (const float*)d_in[1];
  const float* h0    = (const float*)d_in[2];
  const float* c0    = (const float*)d_in[3];
  const float* Win   = (const float*)d_in[4];
  const float* Wre   = (const float*)d_in[5];
  const float* bias  = (const float*)d_in[6];
  float* out = (float*)d_out;

  char* ws = (char*)d_ws;
  unsigned short* Xbf    = (unsigned short*)(ws);                         // 64 MB (dead after gemm)
  unsigned short* WinT   = (unsigned short*)(ws + 67108864);              // 8 MB
  unsigned short* WreT   = (unsigned short*)(ws + 75497472);              // 8 MB
  unsigned short* intern = (unsigned short*)(ws + 83886080);              // 256 MB
  unsigned*       hw     = (unsigned*)(ws);                               // 128 KB tagged h, overlays Xbf

  float* Y = out;
  float* C = out + (size_t)T_STEPS * BATCH * NH_D;
  float* D = out + (size_t)2 * T_STEPS * BATCH * NH_D;

  {
    int n4 = (MROWS * NIN_D) / 4;
    cast_f32_bf16<<<dim3((n4 + 255) / 256), dim3(256), 0, stream>>>(X, Xbf, n4);
  }
  transpose_cast<<<dim3(G_D / 32, NIN_D / 32), dim3(32, 8), 0, stream>>>(Win, WinT);
  transpose_cast<<<dim3(G_D / 32, NH_D / 32),  dim3(32, 8), 0, stream>>>(Wre, WreT);

  gemm_intern<<<dim3(G_D / 128, MROWS / 128), dim3(256), 0, stream>>>(Xbf, WinT, bias, intern);

  // hw overlays the (now dead) Xbf region; reset tags AFTER gemm, every launch
  init_state<<<dim3(64), dim3(256), 0, stream>>>(h0, hw);

  lstm_scan<<<dim3(NWG), dim3(WGT), 0, stream>>>(intern, WreT, imask, c0, hw, Y, C, D);
}